// Round 17
// baseline (584.371 us; speedup 1.0000x reference)
//
#include <hip/hip_runtime.h>
#include <hip/hip_bf16.h>

typedef __attribute__((ext_vector_type(8))) short bf16x8;
typedef __attribute__((ext_vector_type(4))) float f32x4;
typedef __attribute__((ext_vector_type(16))) float f32x16;

static constexpr int BB = 256;   // batch
static constexpr int TT = 33;    // time (input)
static constexpr int EE = 1024;  // embed
static constexpr int LL = 32;    // scan steps = T-1
static constexpr int NG = 4096;  // 4*E gate rows

static constexpr int BUF_SZ  = 24576;    // 16KB W fp32 + 8KB A bf16
static constexpr int A_OFF   = 16384;
static constexpr int NBUF    = 6;
static constexpr int LDS_DYN = 147456;

__device__ __forceinline__ short f2bf(float f) {
  unsigned u = __builtin_bit_cast(unsigned, f);
  u += 0x7fffu + ((u >> 16) & 1u);   // RNE
  return (short)(u >> 16);
}

__device__ __forceinline__ bf16x8 cvt8(f32x4 a, f32x4 b) {
  bf16x8 r;
  r[0] = f2bf(a[0]); r[1] = f2bf(a[1]); r[2] = f2bf(a[2]); r[3] = f2bf(a[3]);
  r[4] = f2bf(b[0]); r[5] = f2bf(b[1]); r[6] = f2bf(b[2]); r[7] = f2bf(b[3]);
  return r;
}

__device__ __forceinline__ float sigm(float x) { return 1.0f / (1.0f + __expf(-x)); }
__device__ __forceinline__ float tanh_f(float x) { return 1.0f - 2.0f / (__expf(2.0f * x) + 1.0f); }

// ---- prep: x fp32 -> bf16 [t][row][e]; c0 = x[:,1,:]; zero 256 flags (sc1)
__global__ __launch_bounds__(256) void lstm_prep(
    const float* __restrict__ x, short* __restrict__ xbf, float* __restrict__ c_io,
    unsigned* __restrict__ flags)
{
  if (blockIdx.x == 0)
    __hip_atomic_store(&flags[(size_t)threadIdx.x * 64], 0u,
                       __ATOMIC_RELAXED, __HIP_MEMORY_SCOPE_AGENT);
  int gth = blockIdx.x * 256 + threadIdx.x;
  int eb  = gth & 127;
  int row = (gth >> 7) & 255;
  int t   = gth >> 15;
  const float* src = x + ((size_t)row * TT + t) * EE + (eb << 3);
  f32x4 lo = *(const f32x4*)src;
  f32x4 hi = *(const f32x4*)(src + 4);
  *(bf16x8*)(xbf + ((size_t)t * BB + row) * EE + (eb << 3)) = cvt8(lo, hi);
  if (t == 1) {
    float* cd = c_io + (size_t)row * EE + (eb << 3);
    *(f32x4*)cd = lo;
    *(f32x4*)(cd + 4) = hi;
  }
}

// ---- rec: 256 WGs x 512 thr, 144KB dynamic LDS (6 bufs).
// r16 base + EPILOGUE-TAIL OVERLAP: the serial epilogue keeps only the
// reduction (dump/add/gate-write, 3 barriers, no vmcnt drain, no flag).
// Gates persist in the red pair, which the rotation restages exactly at the
// NEXT step's pc0 — so pc0 reads gates (lgkm+barrier closes the WAR vs its
// own stage), updates c, publishes h[t-1] BEFORE its stage issue.
// pc1 entry FIFO: [deferred 6][pub 1][pc0 stage 6] -> uniform vmcnt(6)
// retires deferred+pub for every thread -> barrier -> flag=t.
// Consumer poll (own rowgroup, >= t) stays at pc6: 5 phases of slack.
__global__ __launch_bounds__(512) void lstm_rec(
    const short* __restrict__ xbf,   // [32][256][1024] bf16
    const float* __restrict__ Wih,   // [32][4096][1024]
    const float* __restrict__ Whh,   // [32][4096][1024]
    short* __restrict__ hroll,       // [32][256][1024] bf16 rotating
    float* __restrict__ c_io,        // [256][1024] fp32 (d_out c region)
    float* __restrict__ h_out,       // [256][1024] fp32 (d_out h region)
    unsigned* __restrict__ flags)    // [256] slots, 64-uint spacing
{
  extern __shared__ __align__(16) char smem[];

  const int tid  = threadIdx.x;
  const int lane = tid & 63;
  const int wv   = tid >> 6;      // 0..7
  const int ct   = wv & 1;        // col-tile (32 W-rows = 2 gates)
  const int kh   = wv >> 1;       // k-slice 0..3 within BK=64

  const int wg     = blockIdx.x;        // 0..255
  const int xcd    = wg & 7;
  const int jj     = wg >> 3;
  const int rowgrp = jj & 3;            // 4 x 64 rows
  const int ehi    = jj >> 2;           // 0..7
  const int e0     = (xcd * 8 + ehi) << 4;
  const int row0   = rowgrp << 6;

  // ---- staging constants (r12 proven: W linear-dest swizzled-src, A row-pair)
  size_t wsrc_off[2]; int wdst_off[2];
#pragma unroll
  for (int r = 0; r < 2; ++r) {
    int o = r * 8192 + wv * 1024 + lane * 16;
    int lrow = o >> 8;
    int mwr = ((lrow & 7) << 5) | ((lrow & 8) << 1);
    wsrc_off[r] = (size_t)((lrow >> 4) * EE + e0 + (lrow & 15)) * 4096 + ((o & 255) ^ mwr);
    wdst_off[r] = r * 8192 + wv * 1024;
  }
  size_t asrc_off; int adst_off;
  {
    int o  = wv * 1024 + lane * 16;
    int G  = o >> 4;
    int rp = G >> 4;
    int s  = G & 15;
    int r  = rp * 2 + (s & 1);
    int g  = ((s >> 1) ^ (rp & 7)) & 7;
    asrc_off = (size_t)(row0 + r) * 2048 + g * 16;
    adst_off = A_OFF + o;
  }

  // ---- compute constants (r12)
  const int wrow = ct * 32 + (lane & 31);
  const int mg   = ((wrow & 7) << 5) | ((wrow & 8) << 1);
  const int kW   = kh * 64 + ((lane >> 5) << 5);
  const int woff_lo = wrow * 256 + (kW ^ mg);
  const int woff_hi = wrow * 256 + ((kW + 16) ^ mg);
  const int arow = lane & 31;
  const int rpA  = arow >> 1;
  const int gkh  = kh * 2 + (lane >> 5);
  const int sA   = (2 * gkh + (arow & 1)) ^ ((rpA & 7) << 1);
  const int aoff0 = rpA * 256 + sA * 16;

  // ---- epilogue ownership: row er, adjacent col pair (2ep, 2ep+1)
  const int er = tid & 63;
  const int ep = tid >> 6;              // 0..7
  float c0r = c_io[(size_t)(row0 + er) * EE + e0 + 2 * ep];
  float c1r = c_io[(size_t)(row0 + er) * EE + e0 + 2 * ep + 1];

  f32x16 acc0{}, acc1{};

  auto stageC = [&](int tt, int cc, int buf) {
    const int p  = cc >> 4;
    const int k0 = (cc & 15) << 6;
    const char* Wt = (const char*)((p ? Whh : Wih) + (size_t)tt * NG * EE);
    const char* At = p ? (const char*)(hroll + (size_t)(tt - 1) * BB * EE)
                       : (const char*)(xbf + (size_t)tt * BB * EE);
    char* dst = smem + buf * BUF_SZ;
#pragma unroll
    for (int r = 0; r < 2; ++r)
      __builtin_amdgcn_global_load_lds(
          (const __attribute__((address_space(1))) unsigned int*)(Wt + wsrc_off[r] + (k0 << 2)),
          (__attribute__((address_space(3))) unsigned int*)(dst + wdst_off[r]), 16, 0, 0);
    __builtin_amdgcn_global_load_lds(
        (const __attribute__((address_space(1))) unsigned int*)(At + asrc_off + (k0 << 1)),
        (__attribute__((address_space(3))) unsigned int*)(dst + adst_off), 16, 0, 0);
  };

  auto compute = [&](int buf) {
    const char* Wb = smem + buf * BUF_SZ;
    const char* Ab = Wb + A_OFF;
    f32x4 wlo = *(const f32x4*)(Wb + woff_lo);
    f32x4 whi = *(const f32x4*)(Wb + woff_hi);
    bf16x8 bfr = cvt8(wlo, whi);
    bf16x8 a0 = *(const bf16x8*)(Ab + aoff0);
    bf16x8 a1 = *(const bf16x8*)(Ab + aoff0 + 4096);
    acc0 = __builtin_amdgcn_mfma_f32_32x32x16_bf16(a0, bfr, acc0, 0, 0, 0);
    acc1 = __builtin_amdgcn_mfma_f32_32x32x16_bf16(a1, bfr, acc1, 0, 0, 0);
  };

  const int rsw = ((lane >> 1) & 3) << 4;   // 8-way-min reduction swizzle (r12)
  auto dumpT = [&](float* base, const f32x16& a) {
    char* b = (char*)base + lane * 64;
#pragma unroll
    for (int jq = 0; jq < 4; ++jq) {
      f32x4 v{a[jq * 4 + 0], a[jq * 4 + 1], a[jq * 4 + 2], a[jq * 4 + 3]};
      *(f32x4*)(b + ((jq * 16) ^ rsw)) = v;
    }
  };
  auto addT = [&](const float* base, f32x16& a) {
    const char* b = (const char*)base + lane * 64;
#pragma unroll
    for (int jq = 0; jq < 4; ++jq) {
      f32x4 v = *(const f32x4*)(b + ((jq * 16) ^ rsw));
      a[jq * 4 + 0] += v[0]; a[jq * 4 + 1] += v[1];
      a[jq * 4 + 2] += v[2]; a[jq * 4 + 3] += v[3];
    }
  };

  // gate read from the red area (swizzled [wcol][row] matrix)
  auto gateRd = [&](const char* red, int g, int ee) {
    int wc = g * 16 + ee;
    int swc = ((wc & 7) << 5) | ((wc & 8) << 1);
    return *(const float*)(red + wc * 256 + ((er * 4) ^ swc));
  };

  // prologue: stage pairs 0,1 (chunks 0-3)
  stageC(0, 0, 0); stageC(0, 1, 1); stageC(0, 2, 2); stageC(0, 3, 3);

  int fb = 0;
  for (int t = 0; t < LL; ++t) {
    const int nch = t ? 32 : 16;
    const int np  = nch >> 1;
    for (int pc = 0; pc < np; ++pc) {
      bool full = (t == LL - 1 && pc == np - 1);
      if (full) asm volatile("s_waitcnt vmcnt(0) lgkmcnt(0)" ::: "memory");
      else      asm volatile("s_waitcnt vmcnt(6) lgkmcnt(0)" ::: "memory");
      __builtin_amdgcn_s_barrier();

      if (pc == 0 && t > 0) {
        // ---- overlapped epilogue tail of step t-1: gates live in the red pair
        // (fb+4)%6,(fb+5)%6 — the exact bufs THIS phase restages, so read first.
        const char* red = smem + (size_t)((fb + 4) % NBUF) * BUF_SZ;
        int e0c = 2 * ep;
        float gi0 = gateRd(red, 0, e0c),     gf0 = gateRd(red, 1, e0c);
        float gg0 = gateRd(red, 2, e0c),     go0 = gateRd(red, 3, e0c);
        float gi1 = gateRd(red, 0, e0c + 1), gf1 = gateRd(red, 1, e0c + 1);
        float gg1 = gateRd(red, 2, e0c + 1), go1 = gateRd(red, 3, e0c + 1);
        asm volatile("s_waitcnt lgkmcnt(0)" ::: "memory");
        __builtin_amdgcn_s_barrier();        // ALL waves' reads done before any stage

        c0r = sigm(gf0) * c0r + sigm(gi0) * tanh_f(gg0);
        float h0n = sigm(go0) * tanh_f(c0r);
        c1r = sigm(gf1) * c1r + sigm(gi1) * tanh_f(gg1);
        float h1n = sigm(go1) * tanh_f(c1r);
        unsigned pv = (unsigned)(unsigned short)f2bf(h0n)
                    | ((unsigned)(unsigned short)f2bf(h1n) << 16);
        // publish h[t-1]; issued BEFORE this phase's stage -> pc1's vmcnt(6)
        // ([def 6][pub 1][pc0 stage 6] outstanding) proves it retired.
        __hip_atomic_store(
            (unsigned*)((char*)hroll + ((size_t)(t - 1) * BB + row0 + er) * 2048 + (size_t)(e0 + e0c) * 2),
            pv, __ATOMIC_RELAXED, __HIP_MEMORY_SCOPE_AGENT);
      }
      if (pc == 1 && t > 0) {
        if (tid == 0)
          __hip_atomic_store(flags + (size_t)wg * 64, (unsigned)t,
                             __ATOMIC_RELAXED, __HIP_MEMORY_SCOPE_AGENT);
      }

      // stage pair pc+2 (targets bufs freed by the entry barrier)
      int sc0 = 2 * pc + 4, st = t;
      if (sc0 >= nch) { sc0 -= nch; st = t + 1; }
      bool skip = (st > t && sc0 == 2) || (st >= LL);   // pair {2,3} deferred
      if (!skip) {
        if (st == t && sc0 == 16) {        // phase-B pair needs OWN rowgroup h[t-1]
          if (tid < 64) {
            unsigned fid = (unsigned)((tid & 7) + 8 * rowgrp + 32 * (tid >> 3));
            while (__hip_atomic_load(flags + (size_t)fid * 64,
                                     __ATOMIC_RELAXED, __HIP_MEMORY_SCOPE_AGENT) < (unsigned)t)
              __builtin_amdgcn_s_sleep(1);
          }
          __builtin_amdgcn_s_barrier();
          __builtin_amdgcn_sched_barrier(0);
        }
        stageC(st, sc0,     (fb + 4) % NBUF);
        stageC(st, sc0 + 1, (fb + 5) % NBUF);
      }

      compute(fb);
      compute(fb + 1);
      fb = (fb + 2) % NBUF;
    }

    // ---- epilogue: reduction ONLY (3 barriers, no vmcnt drain, no flag)
    asm volatile("s_waitcnt lgkmcnt(0)" ::: "memory");   // final-phase reads done
    __builtin_amdgcn_s_barrier();
    char* red = smem + (size_t)((fb + 4) % NBUF) * BUF_SZ;
    auto slotp = [&](int src, int rt) {
      return (float*)(red + (size_t)((src * 2 + ct) * 2 + rt) * 4096);
    };

    if (kh >= 1) { dumpT(slotp(kh - 1, 0), acc0); dumpT(slotp(kh - 1, 1), acc1); }
    asm volatile("s_waitcnt lgkmcnt(0)" ::: "memory");
    __builtin_amdgcn_s_barrier();

    if (kh == 0) {
#pragma unroll
      for (int src = 0; src < 3; ++src) { addT(slotp(src, 0), acc0); addT(slotp(src, 1), acc1); }
      char* gb = red + wrow * 256;       // gate matrix [wcol][row]; overlays OWN slots
#pragma unroll
      for (int rt = 0; rt < 2; ++rt) {
        const f32x16& a = rt ? acc1 : acc0;
#pragma unroll
        for (int jq = 0; jq < 4; ++jq) {
          int rowb = rt * 128 + jq * 32 + ((lane >> 5) << 4);
          f32x4 v{a[jq * 4 + 0], a[jq * 4 + 1], a[jq * 4 + 2], a[jq * 4 + 3]};
          *(f32x4*)(gb + (rowb ^ mg)) = v;
        }
      }
    }
    acc0 = f32x16{}; acc1 = f32x16{};
    asm volatile("s_waitcnt lgkmcnt(0)" ::: "memory");
    __builtin_amdgcn_s_barrier();

    if (t < LL - 1) {
      // deferred pair (t+1, chunks 2,3); gates stay live in red until t+1 pc0
      stageC(t + 1, 2, (fb + 2) % NBUF);
      stageC(t + 1, 3, (fb + 3) % NBUF);
    }
  }

  // ---- final epilogue (t = LL-1 gates): direct fp32 outputs, no publish
  {
    const char* red = smem + (size_t)((fb + 4) % NBUF) * BUF_SZ;
    int e0c = 2 * ep;
    float gi0 = gateRd(red, 0, e0c),     gf0 = gateRd(red, 1, e0c);
    float gg0 = gateRd(red, 2, e0c),     go0 = gateRd(red, 3, e0c);
    float gi1 = gateRd(red, 0, e0c + 1), gf1 = gateRd(red, 1, e0c + 1);
    float gg1 = gateRd(red, 2, e0c + 1), go1 = gateRd(red, 3, e0c + 1);

    c0r = sigm(gf0) * c0r + sigm(gi0) * tanh_f(gg0);
    float h0n = sigm(go0) * tanh_f(c0r);
    c1r = sigm(gf1) * c1r + sigm(gi1) * tanh_f(gg1);
    float h1n = sigm(go1) * tanh_f(c1r);

    size_t o0 = (size_t)(row0 + er) * EE + e0 + e0c;
    h_out[o0] = h0n;     c_io[o0] = c0r;
    h_out[o0 + 1] = h1n; c_io[o0 + 1] = c1r;
  }
}

__global__ __launch_bounds__(256) void lstm_loss_part(
    const float* __restrict__ h, const float* __restrict__ tgt, float* __restrict__ partials)
{
  __shared__ float lds[4];
  int tid = threadIdx.x;
  float s = 0.f;
  int base = blockIdx.x * 1024 + tid;
#pragma unroll
  for (int q = 0; q < 4; ++q) {
    int idx = base + (q << 8);
    s += fabsf(h[idx] - tgt[idx]);
  }
#pragma unroll
  for (int off = 32; off > 0; off >>= 1) s += __shfl_down(s, off, 64);
  if ((tid & 63) == 0) lds[tid >> 6] = s;
  __syncthreads();
  if (tid == 0) partials[blockIdx.x] = lds[0] + lds[1] + lds[2] + lds[3];
}

__global__ __launch_bounds__(256) void lstm_loss_fin(
    const float* __restrict__ partials, float* __restrict__ out)
{
  __shared__ float lds[4];
  int tid = threadIdx.x;
  float s = partials[tid];
#pragma unroll
  for (int off = 32; off > 0; off >>= 1) s += __shfl_down(s, off, 64);
  if ((tid & 63) == 0) lds[tid >> 6] = s;
  __syncthreads();
  if (tid == 0) out[0] = (lds[0] + lds[1] + lds[2] + lds[3]) * (1.0f / 262144.0f);
}

extern "C" void kernel_launch(void* const* d_in, const int* in_sizes, int n_in,
                              void* d_out, int out_size, void* d_ws, size_t ws_size,
                              hipStream_t stream) {
  const float* x   = (const float*)d_in[0];
  const float* tgt = (const float*)d_in[1];
  const float* Wih = (const float*)d_in[2];
  const float* Whh = (const float*)d_in[3];

  float* out   = (float*)d_out;
  float* h_out = out + 1;                 // [256*1024]
  float* c_io  = out + 1 + BB * EE;       // [256*1024]

  // ws: xbf (16.8MB) | hroll 32 slots (16.8MB) | partials (1KB) | flags (64KB)
  short* xbf      = (short*)d_ws;
  short* hroll    = (short*)((char*)xbf + (size_t)LL * BB * EE * 2);
  float* partials = (float*)((char*)hroll + (size_t)LL * BB * EE * 2);
  unsigned* flags = (unsigned*)((char*)partials + 1024);

  static bool attr_done = false;
  if (!attr_done) {
    hipFuncSetAttribute((const void*)lstm_rec,
                        hipFuncAttributeMaxDynamicSharedMemorySize, LDS_DYN);
    attr_done = true;
  }

  lstm_prep<<<4096, 256, 0, stream>>>(x, xbf, c_io, flags);

  {
    const short* xbfA = xbf; const float* WihA = Wih; const float* WhhA = Whh;
    short* hrollA = hroll; float* cA = c_io; float* hA = h_out; unsigned* flagsA = flags;
    void* args[] = {&xbfA, &WihA, &WhhA, &hrollA, &cA, &hA, &flagsA};
    hipError_t e = hipLaunchCooperativeKernel((void*)lstm_rec, dim3(256), dim3(512),
                                              args, LDS_DYN, stream);
    if (e != hipSuccess)   // insurance vs silent coop rejection
      lstm_rec<<<256, 512, LDS_DYN, stream>>>(xbf, Wih, Whh, hroll, c_io, h_out, flags);
  }

  lstm_loss_part<<<256, 256, 0, stream>>>(h_out, tgt, partials);
  lstm_loss_fin<<<1, 256, 0, stream>>>(partials, out);
}

// Round 18
// 544.474 us; speedup vs baseline: 1.0733x; 1.0733x over previous
//
#include <hip/hip_runtime.h>
#include <hip/hip_bf16.h>

typedef __attribute__((ext_vector_type(8))) short bf16x8;
typedef __attribute__((ext_vector_type(4))) float f32x4;
typedef __attribute__((ext_vector_type(16))) float f32x16;

static constexpr int BB = 256;   // batch
static constexpr int TT = 33;    // time (input)
static constexpr int EE = 1024;  // embed
static constexpr int LL = 32;    // scan steps = T-1
static constexpr int NG = 4096;  // 4*E gate rows

static constexpr int BUF_SZ  = 24576;    // 16KB W fp32 + 8KB A bf16
static constexpr int A_OFF   = 16384;
static constexpr int NBUF    = 6;
static constexpr int LDS_DYN = 147456;   // 6 bufs; epilogue aliases 2 idle bufs

__device__ __forceinline__ short f2bf(float f) {
  unsigned u = __builtin_bit_cast(unsigned, f);
  u += 0x7fffu + ((u >> 16) & 1u);   // RNE
  return (short)(u >> 16);
}

__device__ __forceinline__ bf16x8 cvt8(f32x4 a, f32x4 b) {
  bf16x8 r;
  r[0] = f2bf(a[0]); r[1] = f2bf(a[1]); r[2] = f2bf(a[2]); r[3] = f2bf(a[3]);
  r[4] = f2bf(b[0]); r[5] = f2bf(b[1]); r[6] = f2bf(b[2]); r[7] = f2bf(b[3]);
  return r;
}

__device__ __forceinline__ float sigm(float x) { return 1.0f / (1.0f + __expf(-x)); }
__device__ __forceinline__ float tanh_f(float x) { return 1.0f - 2.0f / (__expf(2.0f * x) + 1.0f); }

// ---- prep: x fp32 -> bf16 [t][row][e]; c0 = x[:,1,:]; zero 256 flags
__global__ __launch_bounds__(256) void lstm_prep(
    const float* __restrict__ x, short* __restrict__ xbf, float* __restrict__ c_io,
    unsigned* __restrict__ flags)
{
  if (blockIdx.x == 0) flags[(size_t)threadIdx.x * 64] = 0;
  int gth = blockIdx.x * 256 + threadIdx.x;
  int eb  = gth & 127;
  int row = (gth >> 7) & 255;
  int t   = gth >> 15;
  const float* src = x + ((size_t)row * TT + t) * EE + (eb << 3);
  f32x4 lo = *(const f32x4*)src;
  f32x4 hi = *(const f32x4*)(src + 4);
  *(bf16x8*)(xbf + ((size_t)t * BB + row) * EE + (eb << 3)) = cvt8(lo, hi);
  if (t == 1) {
    float* cd = c_io + (size_t)row * EE + (eb << 3);
    *(f32x4*)cd = lo;
    *(f32x4*)(cd + 4) = hi;
  }
}

// ---- rec: 256 WGs x 512 thr, 144KB dynamic LDS (6 bufs).
// PAIR pipeline: 2 chunks per {vmcnt(6) -> barrier -> compute x2 -> stage pair}.
// A stored row-pair interleaved (256B pairs, s = (2g+(r&1)) ^ ((rp&7)<<1)):
// k-slice reads spread 16 granule slots -> 2-way (free). W layout unchanged.
// Epilogue: kh-partial tree-reduction in the 2 just-freed bufs (flat mod-6 safe),
// reduction swizzle ((lane>>1)&3)<<4 = 8-way min. Publish/flag protocol proven r8-r11.
__global__ __launch_bounds__(512) void lstm_rec(
    const short* __restrict__ xbf,   // [32][256][1024] bf16
    const float* __restrict__ Wih,   // [32][4096][1024]
    const float* __restrict__ Whh,   // [32][4096][1024]
    short* __restrict__ hroll,       // [32][256][1024] bf16 rotating
    float* __restrict__ c_io,        // [256][1024] fp32 (d_out c region)
    float* __restrict__ h_out,       // [256][1024] fp32 (d_out h region)
    unsigned* __restrict__ flags)    // [256] slots, 64-uint spacing
{
  extern __shared__ __align__(16) char smem[];

  const int tid  = threadIdx.x;
  const int lane = tid & 63;
  const int wv   = tid >> 6;      // 0..7
  const int ct   = wv & 1;        // col-tile (32 W-rows = 2 gates)
  const int kh   = wv >> 1;       // k-slice 0..3 within BK=64

  const int wg     = blockIdx.x;        // 0..255
  const int xcd    = wg & 7;
  const int jj     = wg >> 3;
  const int rowgrp = jj & 3;            // 4 x 64 rows
  const int ehi    = jj >> 2;           // 0..7
  const int e0     = (xcd * 8 + ehi) << 4;
  const int row0   = rowgrp << 6;

  // ---- staging constants: W identical to r9/r11; A = row-pair interleave inverse
  size_t wsrc_off[2]; int wdst_off[2];
#pragma unroll
  for (int r = 0; r < 2; ++r) {
    int o = r * 8192 + wv * 1024 + lane * 16;
    int lrow = o >> 8;
    int mwr = ((lrow & 7) << 5) | ((lrow & 8) << 1);
    wsrc_off[r] = (size_t)((lrow >> 4) * EE + e0 + (lrow & 15)) * 4096 + ((o & 255) ^ mwr);
    wdst_off[r] = r * 8192 + wv * 1024;
  }
  size_t asrc_off; int adst_off;
  {
    int o  = wv * 1024 + lane * 16;     // dest byte in A region (linear)
    int G  = o >> 4;                    // granule 0..511
    int rp = G >> 4;                    // row-pair 0..31
    int s  = G & 15;
    int r  = rp * 2 + (s & 1);
    int g  = ((s >> 1) ^ (rp & 7)) & 7;
    asrc_off = (size_t)(row0 + r) * 2048 + g * 16;
    adst_off = A_OFF + o;
  }

  // ---- compute constants
  const int wrow    = ct * 32 + (lane & 31);
  const int mwr2    = ((wrow & 7) << 5) | ((wrow & 8) << 1);
  const int kW      = kh * 64 + ((lane >> 5) << 5);
  const int woff_lo = wrow * 256 + (kW ^ mwr2);
  const int woff_hi = wrow * 256 + ((kW + 16) ^ mwr2);
  const int arow    = lane & 31;
  const int rpA     = arow >> 1;
  const int gkh     = kh * 2 + (lane >> 5);
  const int sA      = (2 * gkh + (arow & 1)) ^ ((rpA & 7) << 1);
  const int aoff0   = rpA * 256 + sA * 16;     // +4096 for rows 32..63

  // ---- epilogue element ownership
  const int er  = tid & 63;
  const int ee_ = tid >> 6;             // 0..7
  float c0r = c_io[(size_t)(row0 + er) * EE + e0 + ee_];
  float c1r = c_io[(size_t)(row0 + er) * EE + e0 + ee_ + 8];

  f32x16 acc0{}, acc1{};   // k-partials (rows 0-31, 32-63)

  auto stageC = [&](int tt, int cc, int buf) {
    const int p  = cc >> 4;             // 0: x@Wih, 1: h@Whh
    const int k0 = (cc & 15) << 6;
    const char* Wt = (const char*)((p ? Whh : Wih) + (size_t)tt * NG * EE);
    const char* At = p ? (const char*)(hroll + (size_t)(tt - 1) * BB * EE)
                       : (const char*)(xbf + (size_t)tt * BB * EE);
    char* dst = smem + buf * BUF_SZ;
#pragma unroll
    for (int r = 0; r < 2; ++r)
      __builtin_amdgcn_global_load_lds(
          (const __attribute__((address_space(1))) unsigned int*)(Wt + wsrc_off[r] + (k0 << 2)),
          (__attribute__((address_space(3))) unsigned int*)(dst + wdst_off[r]), 16, 0, 0);
    __builtin_amdgcn_global_load_lds(
        (const __attribute__((address_space(1))) unsigned int*)(At + asrc_off + (k0 << 1)),
        (__attribute__((address_space(3))) unsigned int*)(dst + adst_off), 16, 0, 0);
  };

  auto compute = [&](int buf) {
    const char* Wb = smem + buf * BUF_SZ;
    const char* Ab = Wb + A_OFF;
    f32x4 wlo = *(const f32x4*)(Wb + woff_lo);
    f32x4 whi = *(const f32x4*)(Wb + woff_hi);
    bf16x8 bfr = cvt8(wlo, whi);
    bf16x8 a0 = *(const bf16x8*)(Ab + aoff0);
    bf16x8 a1 = *(const bf16x8*)(Ab + aoff0 + 4096);
    acc0 = __builtin_amdgcn_mfma_f32_32x32x16_bf16(a0, bfr, acc0, 0, 0, 0);
    acc1 = __builtin_amdgcn_mfma_f32_32x32x16_bf16(a1, bfr, acc1, 0, 0, 0);
  };

  const int rsw = ((lane >> 1) & 3) << 4;   // 8-way min (was 16-way)
  auto dumpT = [&](float* base, const f32x16& a) {
    char* b = (char*)base + lane * 64;
#pragma unroll
    for (int jq = 0; jq < 4; ++jq) {
      f32x4 v{a[jq * 4 + 0], a[jq * 4 + 1], a[jq * 4 + 2], a[jq * 4 + 3]};
      *(f32x4*)(b + ((jq * 16) ^ rsw)) = v;
    }
  };
  auto addT = [&](const float* base, f32x16& a) {
    const char* b = (const char*)base + lane * 64;
#pragma unroll
    for (int jq = 0; jq < 4; ++jq) {
      f32x4 v = *(const f32x4*)(b + ((jq * 16) ^ rsw));
      a[jq * 4 + 0] += v[0]; a[jq * 4 + 1] += v[1];
      a[jq * 4 + 2] += v[2]; a[jq * 4 + 3] += v[3];
    }
  };

  // prologue: stage pairs 0,1 (chunks 0-3)
  stageC(0, 0, 0); stageC(0, 1, 1); stageC(0, 2, 2); stageC(0, 3, 3);

  int fb = 0;   // buf index of current pair's first chunk (flat chunk % 6)
  for (int t = 0; t < LL; ++t) {
    const int nch = t ? 32 : 16;
    for (int pc = 0; pc < nch / 2; ++pc) {
      if (t == LL - 1 && pc == nch / 2 - 1) asm volatile("s_waitcnt vmcnt(0)" ::: "memory");
      else                                   asm volatile("s_waitcnt vmcnt(6)" ::: "memory");
      __builtin_amdgcn_s_barrier();
      compute(fb);
      compute((fb + 1) % NBUF);

      int sc0 = 2 * pc + 4, st = t;
      if (sc0 >= nch) { sc0 -= nch; st = t + 1; }
      bool skip = (st > t && sc0 == 2) || (st >= LL);   // pair {2,3} deferred
      if (!skip) {
        if (st == t && sc0 == 16) {        // first phase-B pair needs h[t-1]
          if (tid < 256) {
            while (__hip_atomic_load(flags + (size_t)tid * 64,
                                     __ATOMIC_RELAXED, __HIP_MEMORY_SCOPE_AGENT) < (unsigned)t)
              __builtin_amdgcn_s_sleep(1);
          }
          __builtin_amdgcn_s_barrier();
          __builtin_amdgcn_sched_barrier(0);
        }
        stageC(st, sc0,     (fb + 4) % NBUF);
        stageC(st, sc0 + 1, (fb + 5) % NBUF);
      }
      fb = (fb + 2) % NBUF;
    }

    // ---- epilogue: red = last pair's c0 buf, ldsg/hh = last pair's c1 buf
    float* red  = (float*)(smem + (size_t)((fb + 4) % NBUF) * BUF_SZ);
    char*  glsb = smem + (size_t)((fb + 5) % NBUF) * BUF_SZ;
    auto slotp = [&](int src, int rt) { return red + (size_t)((ct * 2 + src) * 2 + rt) * 1024; };

    if (kh >= 2) { dumpT(slotp(kh - 2, 0), acc0); dumpT(slotp(kh - 2, 1), acc1); }
    asm volatile("s_waitcnt lgkmcnt(0)" ::: "memory");
    __builtin_amdgcn_s_barrier();
    if (kh < 2) { addT(slotp(kh, 0), acc0); addT(slotp(kh, 1), acc1); }
    asm volatile("s_waitcnt lgkmcnt(0)" ::: "memory");
    __builtin_amdgcn_s_barrier();
    if (kh == 1) { dumpT(slotp(0, 0), acc0); dumpT(slotp(0, 1), acc1); }
    asm volatile("s_waitcnt lgkmcnt(0)" ::: "memory");
    __builtin_amdgcn_s_barrier();
    if (kh == 0) {
      addT(slotp(0, 0), acc0);
      addT(slotp(0, 1), acc1);
      char* gb = glsb + wrow * 256;       // gate matrix [wcol][row], swizzled
#pragma unroll
      for (int rt = 0; rt < 2; ++rt) {
        const f32x16& a = rt ? acc1 : acc0;
#pragma unroll
        for (int jq = 0; jq < 4; ++jq) {
          int rowb = rt * 128 + jq * 32 + ((lane >> 5) << 4);
          f32x4 v{a[jq * 4 + 0], a[jq * 4 + 1], a[jq * 4 + 2], a[jq * 4 + 3]};
          *(f32x4*)(gb + (rowb ^ mwr2)) = v;
        }
      }
    }
    acc0 = f32x16{}; acc1 = f32x16{};
    asm volatile("s_waitcnt lgkmcnt(0)" ::: "memory");
    __builtin_amdgcn_s_barrier();

    {
      short* hh = (short*)(glsb + 16384);
      auto gate = [&](int g, int ee) {
        int wc = g * 16 + ee;
        int swc = ((wc & 7) << 5) | ((wc & 8) << 1);
        return *(const float*)(glsb + wc * 256 + ((er * 4) ^ swc));
      };
      float gi0 = gate(0, ee_), gf0 = gate(1, ee_), gg0 = gate(2, ee_), go0 = gate(3, ee_);
      float gi1 = gate(0, ee_ + 8), gf1 = gate(1, ee_ + 8), gg1 = gate(2, ee_ + 8), go1 = gate(3, ee_ + 8);

      c0r = sigm(gf0) * c0r + sigm(gi0) * tanh_f(gg0);
      float h0n = sigm(go0) * tanh_f(c0r);
      c1r = sigm(gf1) * c1r + sigm(gi1) * tanh_f(gg1);
      float h1n = sigm(go1) * tanh_f(c1r);

      hh[er * 16 + ee_]     = f2bf(h0n);
      hh[er * 16 + ee_ + 8] = f2bf(h1n);

      if (t == LL - 1) {
        size_t o0 = (size_t)(row0 + er) * EE + e0 + ee_;
        size_t o1 = o0 + 8;
        h_out[o0] = h0n; c_io[o0] = c0r;
        h_out[o1] = h1n; c_io[o1] = c1r;
      }
    }
    asm volatile("s_waitcnt lgkmcnt(0)" ::: "memory");
    __builtin_amdgcn_s_barrier();

    if (t < LL - 1) {
      // publish h[t] (sc1 -> L3), deferred pair (t+1,{2,3}), vmcnt(6) proof, flag
      if (tid < 256) {
        int r = tid >> 2, q = tid & 3;
        unsigned long long v = *(const unsigned long long*)(glsb + 16384 + r * 32 + q * 8);
        __hip_atomic_store(
            (unsigned long long*)((char*)hroll + ((size_t)t * BB + row0 + r) * 2048 + (size_t)e0 * 2 + q * 8),
            v, __ATOMIC_RELAXED, __HIP_MEMORY_SCOPE_AGENT);
      }
      stageC(t + 1, 2, (fb + 2) % NBUF);
      stageC(t + 1, 3, (fb + 3) % NBUF);
      asm volatile("s_waitcnt vmcnt(6)" ::: "memory");   // FIFO: publish retired
      __builtin_amdgcn_s_barrier();                      // ...for all waves
      if (tid == 0)
        __hip_atomic_store(flags + (size_t)wg * 64, (unsigned)(t + 1),
                           __ATOMIC_RELAXED, __HIP_MEMORY_SCOPE_AGENT);
    }
  }
}

__global__ __launch_bounds__(256) void lstm_loss_part(
    const float* __restrict__ h, const float* __restrict__ tgt, float* __restrict__ partials)
{
  __shared__ float lds[4];
  int tid = threadIdx.x;
  float s = 0.f;
  int base = blockIdx.x * 1024 + tid;
#pragma unroll
  for (int q = 0; q < 4; ++q) {
    int idx = base + (q << 8);
    s += fabsf(h[idx] - tgt[idx]);
  }
#pragma unroll
  for (int off = 32; off > 0; off >>= 1) s += __shfl_down(s, off, 64);
  if ((tid & 63) == 0) lds[tid >> 6] = s;
  __syncthreads();
  if (tid == 0) partials[blockIdx.x] = lds[0] + lds[1] + lds[2] + lds[3];
}

__global__ __launch_bounds__(256) void lstm_loss_fin(
    const float* __restrict__ partials, float* __restrict__ out)
{
  __shared__ float lds[4];
  int tid = threadIdx.x;
  float s = partials[tid];
#pragma unroll
  for (int off = 32; off > 0; off >>= 1) s += __shfl_down(s, off, 64);
  if ((tid & 63) == 0) lds[tid >> 6] = s;
  __syncthreads();
  if (tid == 0) out[0] = (lds[0] + lds[1] + lds[2] + lds[3]) * (1.0f / 262144.0f);
}

extern "C" void kernel_launch(void* const* d_in, const int* in_sizes, int n_in,
                              void* d_out, int out_size, void* d_ws, size_t ws_size,
                              hipStream_t stream) {
  const float* x   = (const float*)d_in[0];
  const float* tgt = (const float*)d_in[1];
  const float* Wih = (const float*)d_in[2];
  const float* Whh = (const float*)d_in[3];

  float* out   = (float*)d_out;
  float* h_out = out + 1;                 // [256*1024]
  float* c_io  = out + 1 + BB * EE;       // [256*1024]

  // ws: xbf (16.8MB) | hroll 32 slots (16.8MB) | partials (1KB) | flags (64KB)
  short* xbf      = (short*)d_ws;
  short* hroll    = (short*)((char*)xbf + (size_t)LL * BB * EE * 2);
  float* partials = (float*)((char*)hroll + (size_t)LL * BB * EE * 2);
  unsigned* flags = (unsigned*)((char*)partials + 1024);

  static bool attr_done = false;
  if (!attr_done) {
    hipFuncSetAttribute((const void*)lstm_rec,
                        hipFuncAttributeMaxDynamicSharedMemorySize, LDS_DYN);
    attr_done = true;
  }

  lstm_prep<<<4096, 256, 0, stream>>>(x, xbf, c_io, flags);

  {
    const short* xbfA = xbf; const float* WihA = Wih; const float* WhhA = Whh;
    short* hrollA = hroll; float* cA = c_io; float* hA = h_out; unsigned* flagsA = flags;
    void* args[] = {&xbfA, &WihA, &WhhA, &hrollA, &cA, &hA, &flagsA};
    hipError_t e = hipLaunchCooperativeKernel((void*)lstm_rec, dim3(256), dim3(512),
                                              args, LDS_DYN, stream);
    if (e != hipSuccess)   // insurance vs silent coop rejection
      lstm_rec<<<256, 512, LDS_DYN, stream>>>(xbf, Wih, Whh, hroll, c_io, h_out, flags);
  }

  lstm_loss_part<<<256, 256, 0, stream>>>(h_out, tgt, partials);
  lstm_loss_fin<<<1, 256, 0, stream>>>(partials, out);
}